// Round 1
// 476.463 us; speedup vs baseline: 1.0170x; 1.0170x over previous
//
#include <hip/hip_runtime.h>

#define NU 50000
#define NI 50000
#define NE 800000
#define NLBL 200000
#define DIN 128
#define HID 256
#define DOUT 128

#define NSLICE 64
#define SLICE_SZ 12500   // 800000 / 64
#define HALF_N 25000

typedef unsigned short ushort_t;
typedef __attribute__((ext_vector_type(8))) short bf16x8;
typedef __attribute__((ext_vector_type(4))) float f32x4;

__device__ __forceinline__ float bf2f(unsigned int u_shifted) {
    union { unsigned int i; float f; } v;
    v.i = u_shifted;
    return v.f;
}
__device__ __forceinline__ float bf_lo(unsigned int u) { return bf2f(u << 16); }
__device__ __forceinline__ float bf_hi(unsigned int u) { return bf2f(u & 0xffff0000u); }
__device__ __forceinline__ ushort_t f2bf(float f) {
    union { float f; unsigned int i; } v;
    v.f = f;
    unsigned int r = (v.i + 0x7FFFu + ((v.i >> 16) & 1u)) >> 16;
    return (ushort_t)r;
}
__device__ __forceinline__ void load_lds16(const ushort_t* g, ushort_t* s) {
    __builtin_amdgcn_global_load_lds(
        (const __attribute__((address_space(1))) void*)g,
        (__attribute__((address_space(3))) void*)s, 16, 0, 0);
}

// ================= prep: input cvt ∥ weight transpose ∥ weight products ∥ bias folds ====
#define CVT_PER 782
#define CVT_B (2 * CVT_PER)
#define TR_B 1536
#define PROD_B 512

struct TJob { const float* W; ushort_t* T; int K; int N; };
struct PrepArgs {
    const float* xu; ushort_t* xbu; const float* xi; ushort_t* xbi;
    TJob tj[10];
    const float *wmui0, *wrui0, *wmiu0, *wriu0, *wmui1, *wmiu1;
    ushort_t *P1, *P2, *Q1, *Q2;  // products, stored transposed [256][128]
    const float *bui0, *biu0, *bui1, *biu1;
    float *b1p, *b2p;
};

__global__ __launch_bounds__(256) void prep_kernel(PrepArgs a) {
    int b = blockIdx.x;
    int t = threadIdx.x;
    if (b < CVT_B) {
        int cb = b;
        int which = (cb >= CVT_PER);
        if (which) cb -= CVT_PER;
        const float4* in = (const float4*)(which ? a.xi : a.xu);
        uint2* outp = (uint2*)(which ? a.xbi : a.xbu);
        const int n4 = NU * DIN / 4;
#pragma unroll
        for (int k = 0; k < 8; ++k) {
            int i = cb * 2048 + k * 256 + t;
            if (i < n4) {
                float4 v = in[i];
                uint2 o;
                o.x = (unsigned int)f2bf(v.x) | ((unsigned int)f2bf(v.y) << 16);
                o.y = (unsigned int)f2bf(v.z) | ((unsigned int)f2bf(v.w) << 16);
                outp[i] = o;
            }
        }
    } else if (b < CVT_B + TR_B) {
        int r = b - CVT_B;
        int j = 0, acc = 0;
        for (; j < 10; ++j) {
            int nb = (a.tj[j].K * a.tj[j].N) >> 8;
            if (r < acc + nb) break;
            acc += nb;
        }
        TJob jb = a.tj[j];
        int e = (r - acc) * 256 + t;
        int k = e / jb.N, n = e - k * jb.N;
        jb.T[(size_t)n * jb.K + k] = f2bf(jb.W[e]);
    } else if (b < CVT_B + TR_B + PROD_B) {
        // weight products, fp32 math: out[k][n] = sum_j amat[k][j]*bmat[j][n], stored T-major
        int r = b - CVT_B - TR_B;
        int pj = r >> 7, k = r & 127, n = t;
        const float* amat = (pj == 0) ? a.wmiu0 : (pj == 1) ? a.wriu0 : (pj == 2) ? a.wmui0 : a.wrui0;
        const float* bmat = (pj < 2) ? a.wmui1 : a.wmiu1;
        ushort_t* outT = (pj == 0) ? a.P1 : (pj == 1) ? a.P2 : (pj == 2) ? a.Q1 : a.Q2;
        float s = 0.f;
#pragma unroll 4
        for (int j = 0; j < HID; ++j) s += amat[k * HID + j] * bmat[j * HID + n];
        outT[(size_t)n * DIN + k] = f2bf(s);
    } else {
        // bias folds: b1p = b_iu0 @ Wm_ui1 + b_ui1 ; b2p = b_ui0 @ Wm_iu1 + b_iu1
        int r2 = b - CVT_B - TR_B - PROD_B;
        const float* bv = r2 ? a.bui0 : a.biu0;
        const float* w = r2 ? a.wmiu1 : a.wmui1;
        const float* badd = r2 ? a.biu1 : a.bui1;
        float* o = r2 ? a.b2p : a.b1p;
        int n = t;
        float s = 0.f;
#pragma unroll 4
        for (int j = 0; j < HID; ++j) s += bv[j] * w[j * HID + n];
        o[n] = s + badd[n];
    }
}

// ================= LDS counting-sort CSR build (ZERO global atomics) =================
__global__ __launch_bounds__(256) void hist_lds(const int* __restrict__ dui,
                                                const int* __restrict__ diu,
                                                ushort_t* __restrict__ cnt_s) {
    __shared__ unsigned int cnt[HALF_N / 2];
    int b = blockIdx.x, t = threadIdx.x;
    int g = b >> 7, s = (b >> 1) & 63, half = b & 1;
    for (int i = t; i < HALF_N / 2; i += 256) cnt[i] = 0;
    __syncthreads();
    const int* dst = g ? diu : dui;
    int hbase = half * HALF_N;
    int e0 = s * SLICE_SZ;
    for (int i = e0 + t; i < e0 + SLICE_SZ; i += 256) {
        int d = dst[i] - hbase;
        if ((unsigned)d < (unsigned)HALF_N)
            atomicAdd(&cnt[d >> 1], 1u << ((d & 1) * 16));
    }
    __syncthreads();
    unsigned int* outp = (unsigned int*)(cnt_s + ((size_t)(g * NSLICE + s)) * 50000 + hbase);
    for (int i = t; i < HALF_N / 2; i += 256) outp[i] = cnt[i];
}

__global__ __launch_bounds__(256) void sscan(ushort_t* __restrict__ cnt_s, int* __restrict__ totals) {
    int idx = blockIdx.x * 256 + threadIdx.x;
    if (idx == 0) totals[100000] = 2 * NE;  // sentinel: end of user-graph csr
    if (idx >= 100000) return;
    int g = idx / 50000, node = idx - g * 50000;
    size_t base = (size_t)g * NSLICE * 50000 + node;
    int run = 0;
#pragma unroll 4
    for (int s = 0; s < NSLICE; ++s) {
        size_t o = base + (size_t)s * 50000;
        int c = cnt_s[o];
        cnt_s[o] = (ushort_t)run;
        run += c;
    }
    totals[idx] = run;
}

__global__ __launch_bounds__(256) void scan1(const int* __restrict__ d, int* __restrict__ part, int n) {
    __shared__ int wsum[4];
    int b = blockIdx.x, t = threadIdx.x;
    int i0 = b * 2048 + t * 8;
    int s = 0;
#pragma unroll
    for (int k = 0; k < 8; ++k) s += (i0 + k < n) ? d[i0 + k] : 0;
#pragma unroll
    for (int off = 32; off > 0; off >>= 1) s += __shfl_down(s, off, 64);
    if ((t & 63) == 0) wsum[t >> 6] = s;
    __syncthreads();
    if (t == 0) part[b] = wsum[0] + wsum[1] + wsum[2] + wsum[3];
}

__global__ __launch_bounds__(256) void scan3(int* __restrict__ d, const int* __restrict__ part,
                                             int n, int nb) {
    __shared__ int wsum[4];
    __shared__ int blockoff_sh;
    int b = blockIdx.x, t = threadIdx.x;
    int lane = t & 63, wv = t >> 6;
    if (t < 64) {
        int v = (t < nb) ? part[t] : 0;
        int incl = v;
#pragma unroll
        for (int off = 1; off < 64; off <<= 1) {
            int tv = __shfl_up(incl, off, 64);
            if (t >= off) incl += tv;
        }
        if (t == b) blockoff_sh = incl - v;
    }
    int i0 = b * 2048 + t * 8;
    int v[8];
    int tsum = 0;
#pragma unroll
    for (int k = 0; k < 8; ++k) {
        v[k] = (i0 + k < n) ? d[i0 + k] : 0;
        tsum += v[k];
    }
    int incl = tsum;
#pragma unroll
    for (int off = 1; off < 64; off <<= 1) {
        int tv = __shfl_up(incl, off, 64);
        if (lane >= off) incl += tv;
    }
    if (lane == 63) wsum[wv] = incl;
    __syncthreads();
    int woff = 0;
    for (int w = 0; w < wv; ++w) woff += wsum[w];
    int run = blockoff_sh + woff + (incl - tsum);
#pragma unroll
    for (int k = 0; k < 8; ++k) {
        if (i0 + k < n) d[i0 + k] = run;
        run += v[k];
    }
}

__global__ __launch_bounds__(256) void fill_lds(const int* __restrict__ eui,
                                                const int* __restrict__ eiu,
                                                const ushort_t* __restrict__ cnt_s,
                                                const int* __restrict__ rowstart,
                                                ushort_t* __restrict__ csr) {
    __shared__ unsigned int off[HALF_N / 2];
    int b = blockIdx.x, t = threadIdx.x;
    int g = b >> 7, s = (b >> 1) & 63, half = b & 1;
    const unsigned int* st =
        (const unsigned int*)(cnt_s + ((size_t)(g * NSLICE + s)) * 50000 + half * HALF_N);
    for (int i = t; i < HALF_N / 2; i += 256) off[i] = st[i];
    __syncthreads();
    const int* src = g ? eiu : eui;
    const int* dst = src + NE;
    const int* rs = rowstart + g * 50000;
    int hbase = half * HALF_N;
    int e0 = s * SLICE_SZ;
    for (int i = e0 + t; i < e0 + SLICE_SZ; i += 256) {
        int dd = dst[i];
        int d = dd - hbase;
        if ((unsigned)d < (unsigned)HALF_N) {
            unsigned old = atomicAdd(&off[d >> 1], 1u << ((d & 1) * 16));
            int rel = (int)((old >> ((d & 1) * 16)) & 0xffffu);
            csr[(size_t)rs[dd] + rel] = (ushort_t)src[i];
        }
    }
}

// ================= DIN=128 gather mean aggregation (bf16, fp32 accum), 2 jobs =================
struct AggJob { const int* sp; const ushort_t* csr; const ushort_t* x; ushort_t* out; int n; };
struct AggJobs2 { AggJob j[2]; };

__global__ __launch_bounds__(256) void agg_din(AggJobs2 js) {
    AggJob jb = js.j[blockIdx.y];
    int wave = (int)((blockIdx.x * 256u + threadIdx.x) >> 6);
    int lane = threadIdx.x & 63;
    const int l = lane & 31;
    const int h = lane >> 5;
    int w2 = wave * 2;
    if (w2 >= jb.n) return;
    int w = w2 + h;
    int s0 = jb.sp[w];
    int s1 = jb.sp[w + 1];
    int cnt = s1 - s0;
    float sc = (cnt > 0) ? 1.0f / (float)cnt : 0.0f;
    int cother = __shfl_xor(cnt, 32, 64);
    int cmax = (cnt > cother) ? cnt : cother;
    const uint2* xp = (const uint2*)jb.x;  // row = 32 uint2
    float f0 = 0.f, f1 = 0.f, f2 = 0.f, f3 = 0.f;
    float g0 = 0.f, g1 = 0.f, g2 = 0.f, g3 = 0.f;
    for (int chunk = 0; chunk < cmax; chunk += 32) {
        int mh = cnt - chunk;
        int safe = (mh > 0) ? ((l < mh) ? l : mh - 1) : 0;
        int vidx = (int)jb.csr[s0 + chunk + safe];
        int mm = cmax - chunk;
        if (mm > 32) mm = 32;
        int j = 0;
        for (; j + 3 < mm; j += 4) {
            int i0 = __shfl(vidx, j, 32);
            int i1 = __shfl(vidx, j + 1, 32);
            int i2 = __shfl(vidx, j + 2, 32);
            int i3 = __shfl(vidx, j + 3, 32);
            float m0 = (j < mh) ? 1.f : 0.f;
            float m1 = (j + 1 < mh) ? 1.f : 0.f;
            float m2 = (j + 2 < mh) ? 1.f : 0.f;
            float m3 = (j + 3 < mh) ? 1.f : 0.f;
            uint2 u0 = xp[(size_t)((j < mh) ? i0 : 0) * 32 + l];
            uint2 u1 = xp[(size_t)((j + 1 < mh) ? i1 : 0) * 32 + l];
            uint2 u2 = xp[(size_t)((j + 2 < mh) ? i2 : 0) * 32 + l];
            uint2 u3 = xp[(size_t)((j + 3 < mh) ? i3 : 0) * 32 + l];
            f0 = fmaf(m0, bf_lo(u0.x), f0); f1 = fmaf(m0, bf_hi(u0.x), f1);
            f2 = fmaf(m0, bf_lo(u0.y), f2); f3 = fmaf(m0, bf_hi(u0.y), f3);
            g0 = fmaf(m1, bf_lo(u1.x), g0); g1 = fmaf(m1, bf_hi(u1.x), g1);
            g2 = fmaf(m1, bf_lo(u1.y), g2); g3 = fmaf(m1, bf_hi(u1.y), g3);
            f0 = fmaf(m2, bf_lo(u2.x), f0); f1 = fmaf(m2, bf_hi(u2.x), f1);
            f2 = fmaf(m2, bf_lo(u2.y), f2); f3 = fmaf(m2, bf_hi(u2.y), f3);
            g0 = fmaf(m3, bf_lo(u3.x), g0); g1 = fmaf(m3, bf_hi(u3.x), g1);
            g2 = fmaf(m3, bf_lo(u3.y), g2); g3 = fmaf(m3, bf_hi(u3.y), g3);
        }
        for (; j < mm; ++j) {
            int i0 = __shfl(vidx, j, 32);
            float m0 = (j < mh) ? 1.f : 0.f;
            uint2 u0 = xp[(size_t)((j < mh) ? i0 : 0) * 32 + l];
            f0 = fmaf(m0, bf_lo(u0.x), f0); f1 = fmaf(m0, bf_hi(u0.x), f1);
            f2 = fmaf(m0, bf_lo(u0.y), f2); f3 = fmaf(m0, bf_hi(u0.y), f3);
        }
    }
    uint2 o;
    o.x = (unsigned int)f2bf((f0 + g0) * sc) | ((unsigned int)f2bf((f1 + g1) * sc) << 16);
    o.y = (unsigned int)f2bf((f2 + g2) * sc) | ((unsigned int)f2bf((f3 + g3) * sc) << 16);
    ((uint2*)jb.out)[(size_t)w * 32 + l] = o;
}

// ================= fused 3-layer GEMM stack =================
// Per 64-row tile: P0 item0 = A1@W0a + A0x@W0b + b0  -> LDS s0 (bf16, XOR-swizzled)
//                  P1 item1 = A2@W1a + A1@W1b + s0@W1c + b1  (acc regs)
//                  P2 z     = s0@W2a (+ overwrite s0 with item1) + s0@W2b + b2 -> global
// item0/item1 never touch HBM. LDS = 32K(s0) + 4K(sA) + 16K(sB) = 52 KB -> 3 blocks/CU.
struct FusedJob {
    const ushort_t* A1;   // level-A agg
    const ushort_t* A0x;  // converted raw features
    const ushort_t* A2;   // level-B agg
    const ushort_t* W0a; const ushort_t* W0b; const float* b0;   // [256][128]
    const ushort_t* W1a; const ushort_t* W1b;                     // [256][128]
    const ushort_t* W1c; const float* b1;                         // [256][256]
    const ushort_t* W2a; const ushort_t* W2b; const float* b2;    // [128][256]
    ushort_t* z;
};
struct FusedJobs2 { FusedJob j[2]; };

// one K=128 part with A from global: stage 64x32 A + 256x32 W per K-step, 16 MFMA/wave
__device__ __forceinline__ void part_g128(const ushort_t* __restrict__ Ap,
                                          const ushort_t* __restrict__ Wp,
                                          ushort_t* sA, ushort_t* sB,
                                          const ushort_t* pA, const ushort_t* pB,
                                          int tid, size_t aoff, size_t boff,
                                          f32x4 (*acc)[4]) {
    for (int k0 = 0; k0 < 128; k0 += 32) {
        __syncthreads();
        load_lds16(Ap + aoff + k0, sA + tid * 8);
#pragma unroll
        for (int i = 0; i < 4; ++i)
            load_lds16(Wp + boff + (size_t)(i * 64) * 128 + k0, sB + i * 2048 + tid * 8);
        __syncthreads();
        bf16x8 af[4], bfr[4];
#pragma unroll
        for (int mt = 0; mt < 4; ++mt) af[mt] = *(const bf16x8*)(pA + mt * 512);
#pragma unroll
        for (int nt = 0; nt < 4; ++nt) bfr[nt] = *(const bf16x8*)(pB + nt * 512);
#pragma unroll
        for (int mt = 0; mt < 4; ++mt)
#pragma unroll
            for (int nt = 0; nt < 4; ++nt)
                acc[mt][nt] = __builtin_amdgcn_mfma_f32_16x16x32_bf16(
                    af[mt], bfr[nt], acc[mt][nt], 0, 0, 0);
    }
}

// one K=256 part with A from swizzled s0; NT=4 -> W[256][256], NT=2 -> W[128][256]
template <int NT>
__device__ __forceinline__ void part_s0(const ushort_t* __restrict__ Wp,
                                        const ushort_t* s0, ushort_t* sB,
                                        const ushort_t* pB,
                                        int tid, int l15, int kl, size_t boff,
                                        f32x4 (*acc)[NT]) {
    for (int k0 = 0; k0 < 256; k0 += 32) {
        __syncthreads();
#pragma unroll
        for (int i = 0; i < NT; ++i)
            load_lds16(Wp + boff + (size_t)(i * 64) * 256 + k0, sB + i * 2048 + tid * 8);
        __syncthreads();
        bf16x8 af[4], bfr[NT];
        int kk = k0 + kl * 8;
#pragma unroll
        for (int mt = 0; mt < 4; ++mt) {
            int row = l15 + mt * 16;
            af[mt] = *(const bf16x8*)(s0 + row * 256 + (((kk >> 3) ^ (row & 7)) << 3));
        }
#pragma unroll
        for (int nt = 0; nt < NT; ++nt) bfr[nt] = *(const bf16x8*)(pB + nt * 512);
#pragma unroll
        for (int mt = 0; mt < 4; ++mt)
#pragma unroll
            for (int nt = 0; nt < NT; ++nt)
                acc[mt][nt] = __builtin_amdgcn_mfma_f32_16x16x32_bf16(
                    af[mt], bfr[nt], acc[mt][nt], 0, 0, 0);
    }
}

// write acc (+bias) as bf16 into s0 with the XOR-16B-chunk swizzle matching part_s0 reads
__device__ __forceinline__ void dump_s0(ushort_t* s0, const float* __restrict__ bias,
                                        int wn, int l15, int kl, f32x4 (*acc)[4]) {
    float bv[4];
#pragma unroll
    for (int nt = 0; nt < 4; ++nt) bv[nt] = bias[wn * 64 + nt * 16 + l15];
#pragma unroll
    for (int mt = 0; mt < 4; ++mt)
#pragma unroll
        for (int r = 0; r < 4; ++r) {
            int row = mt * 16 + kl * 4 + r;
#pragma unroll
            for (int nt = 0; nt < 4; ++nt) {
                int col = wn * 64 + nt * 16 + l15;
                s0[row * 256 + ((((col >> 3) ^ (row & 7)) << 3) | (col & 7))] =
                    f2bf(acc[mt][nt][r] + bv[nt]);
            }
        }
}

__global__ __launch_bounds__(256, 3) void fused_gnn(FusedJobs2 js, int M) {
    FusedJob jb = js.j[blockIdx.y];
    __shared__ ushort_t s0[64 * 256];   // 32 KB intermediate (item0, then item1)
    __shared__ ushort_t sA[64 * 32];    // 4 KB A staging
    __shared__ ushort_t sB[256 * 32];   // 16 KB W staging
    const int tid = threadIdx.x;
    const int lane = tid & 63;
    const int wn = tid >> 6;       // wave: owns 64 cols (P0/P1) / 32 cols (P2)
    const int l15 = lane & 15;
    const int kl = lane >> 4;
    const int rb = blockIdx.x * 64;
    const int srow = tid >> 2;
    const int scol = (tid & 3) * 8;
    int ar = rb + srow; if (ar > M - 1) ar = M - 1;
    const size_t aoff = (size_t)ar * 128 + scol;
    const size_t boff128 = (size_t)srow * 128 + scol;
    const size_t boff256 = (size_t)srow * 256 + scol;
    const ushort_t* pA = sA + l15 * 32 + kl * 8;
    const ushort_t* pB = sB + (wn * 64 + l15) * 32 + kl * 8;
    const ushort_t* pB2 = sB + (wn * 32 + l15) * 32 + kl * 8;

    f32x4 acc[4][4] = {};

    // ---- P0: item0 ----
    part_g128(jb.A1, jb.W0a, sA, sB, pA, pB, tid, aoff, boff128, acc);
    part_g128(jb.A0x, jb.W0b, sA, sB, pA, pB, tid, aoff, boff128, acc);
    dump_s0(s0, jb.b0, wn, l15, kl, acc);   // no hazard: nobody reads s0 yet
#pragma unroll
    for (int mt = 0; mt < 4; ++mt)
#pragma unroll
        for (int nt = 0; nt < 4; ++nt) acc[mt][nt] = (f32x4){0.f, 0.f, 0.f, 0.f};

    // ---- P1: item1 (s0 visible after first barrier of next part) ----
    part_g128(jb.A2, jb.W1a, sA, sB, pA, pB, tid, aoff, boff128, acc);
    part_g128(jb.A1, jb.W1b, sA, sB, pA, pB, tid, aoff, boff128, acc);
    part_s0<4>(jb.W1c, s0, sB, pB, tid, l15, kl, boff256, acc);

    // ---- P2 part 1: z += item0 @ W2a (item0 still in s0) ----
    f32x4 accZ[4][2] = {};
    part_s0<2>(jb.W2a, s0, sB, pB2, tid, l15, kl, boff256, accZ);

    __syncthreads();                        // all waves done reading item0
    dump_s0(s0, jb.b1, wn, l15, kl, acc);   // overwrite with item1 (+folded bias)

    // ---- P2 part 2: z += item1 @ W2b (barrier inside part_s0 orders the dump) ----
    part_s0<2>(jb.W2b, s0, sB, pB2, tid, l15, kl, boff256, accZ);

    // ---- store z ----
    float bz[2];
#pragma unroll
    for (int nt = 0; nt < 2; ++nt) bz[nt] = jb.b2[wn * 32 + nt * 16 + l15];
#pragma unroll
    for (int mt = 0; mt < 4; ++mt)
#pragma unroll
        for (int r = 0; r < 4; ++r) {
            int row = rb + mt * 16 + kl * 4 + r;
            if (row >= M) continue;
#pragma unroll
            for (int nt = 0; nt < 2; ++nt) {
                int col = wn * 32 + nt * 16 + l15;
                jb.z[(size_t)row * DOUT + col] = f2bf(accZ[mt][nt][r] + bz[nt]);
            }
        }
}

// ================= decode: bf16 z, 4 edges per wave (16-lane quarters, uint4) =================
__global__ void decode_kernel(const int* __restrict__ lbl, const ushort_t* __restrict__ zu,
                              const ushort_t* __restrict__ zi, float* __restrict__ out, int n) {
    int gid = blockIdx.x * blockDim.x + threadIdx.x;
    int wave = gid >> 6;
    int lane = threadIdx.x & 63;
    int q = lane >> 4;
    int l = lane & 15;
    int e = wave * 4 + q;
    if (e >= n) return;
    int u = lbl[e];
    int it = lbl[n + e];
    uint4 a = ((const uint4*)zu)[(size_t)u * 16 + l];
    uint4 b = ((const uint4*)zi)[(size_t)it * 16 + l];
    float s = bf_lo(a.x) * bf_lo(b.x) + bf_hi(a.x) * bf_hi(b.x) +
              bf_lo(a.y) * bf_lo(b.y) + bf_hi(a.y) * bf_hi(b.y) +
              bf_lo(a.z) * bf_lo(b.z) + bf_hi(a.z) * bf_hi(b.z) +
              bf_lo(a.w) * bf_lo(b.w) + bf_hi(a.w) * bf_hi(b.w);
#pragma unroll
    for (int off = 8; off > 0; off >>= 1) s += __shfl_down(s, off, 16);
    if (l == 0) out[e] = s;
}

extern "C" void kernel_launch(void* const* d_in, const int* in_sizes, int n_in,
                              void* d_out, int out_size, void* d_ws, size_t ws_size,
                              hipStream_t stream) {
    const float* x_user = (const float*)d_in[0];
    const float* x_item = (const float*)d_in[1];
    const int* edge_ui = (const int*)d_in[2];   // row0=src(user), row1=dst(item)
    const int* edge_iu = (const int*)d_in[3];   // row0=src(item), row1=dst(user)
    const int* edge_lbl = (const int*)d_in[4];
    const float* w_msg_ui0 = (const float*)d_in[5];
    const float* b_ui0 = (const float*)d_in[6];
    const float* w_root_ui0 = (const float*)d_in[7];
    const float* w_msg_iu0 = (const float*)d_in[8];
    const float* b_iu0 = (const float*)d_in[9];
    const float* w_root_iu0 = (const float*)d_in[10];
    const float* w_msg_ui1 = (const float*)d_in[11];
    const float* b_ui1 = (const float*)d_in[12];
    const float* w_root_ui1 = (const float*)d_in[13];
    const float* w_msg_iu1 = (const float*)d_in[14];
    const float* b_iu1 = (const float*)d_in[15];
    const float* w_root_iu1 = (const float*)d_in[16];
    const float* w_lin_u = (const float*)d_in[17];  // [512,128]
    const float* b_lin_u = (const float*)d_in[18];
    const float* w_lin_i = (const float*)d_in[19];
    const float* b_lin_i = (const float*)d_in[20];
    float* out = (float*)d_out;

    // ---- workspace layout (unchanged; item0/user0/item1/user1 slots now unused) ----
    char* p = (char*)d_ws;
    ushort_t* user0 = (ushort_t*)p;  p += (size_t)NU * HID * 2;
    ushort_t* item0 = (ushort_t*)p;  p += (size_t)NI * HID * 2;
    ushort_t* user1 = (ushort_t*)p;  p += (size_t)NU * HID * 2;
    ushort_t* item1 = (ushort_t*)p;  p += (size_t)NI * HID * 2;
    (void)user0; (void)item0; (void)user1; (void)item1;
    ushort_t* A_i  = (ushort_t*)p;   p += (size_t)NI * DIN * 2;  // mean_ui(x_user)
    ushort_t* A_u  = (ushort_t*)p;   p += (size_t)NU * DIN * 2;  // mean_iu(x_item)
    ushort_t* B_i  = (ushort_t*)p;   p += (size_t)NI * DIN * 2;  // mean_ui(A_u)
    ushort_t* B_u  = (ushort_t*)p;   p += (size_t)NU * DIN * 2;  // mean_iu(A_i)
    ushort_t* xb_u  = (ushort_t*)p;  p += (size_t)NU * DIN * 2;
    ushort_t* xb_i  = (ushort_t*)p;  p += (size_t)NI * DIN * 2;
    ushort_t* z_user = (ushort_t*)p; p += (size_t)NU * DOUT * 2;
    ushort_t* z_item = (ushort_t*)p; p += (size_t)NI * DOUT * 2;
    int* totals     = (int*)p;       p += (size_t)(100000 + 64) * 4;  // rowstarts + sentinel
    ushort_t* csr   = (ushort_t*)p;  p += (size_t)2 * NE * 2;  // [0,NE): ui; [NE,2NE): iu
    ushort_t* cnt_s = (ushort_t*)p;  p += (size_t)2 * NSLICE * 50000 * 2;  // per-slice counts
    int* scan_part  = (int*)p;       p += 64 * 4;
    ushort_t* T_msg_ui0 = (ushort_t*)p; p += (size_t)DIN * HID * 2;
    ushort_t* T_root_ui0 = (ushort_t*)p; p += (size_t)DIN * HID * 2;
    ushort_t* T_msg_iu0 = (ushort_t*)p; p += (size_t)DIN * HID * 2;
    ushort_t* T_root_iu0 = (ushort_t*)p; p += (size_t)DIN * HID * 2;
    ushort_t* T_root_ui1 = (ushort_t*)p; p += (size_t)HID * HID * 2;
    ushort_t* T_root_iu1 = (ushort_t*)p; p += (size_t)HID * HID * 2;
    ushort_t* T_lin_u_a = (ushort_t*)p; p += (size_t)HID * DOUT * 2;
    ushort_t* T_lin_u_b = (ushort_t*)p; p += (size_t)HID * DOUT * 2;
    ushort_t* T_lin_i_a = (ushort_t*)p; p += (size_t)HID * DOUT * 2;
    ushort_t* T_lin_i_b = (ushort_t*)p; p += (size_t)HID * DOUT * 2;
    ushort_t* T_P1 = (ushort_t*)p; p += (size_t)HID * DIN * 2;
    ushort_t* T_P2 = (ushort_t*)p; p += (size_t)HID * DIN * 2;
    ushort_t* T_Q1 = (ushort_t*)p; p += (size_t)HID * DIN * 2;
    ushort_t* T_Q2 = (ushort_t*)p; p += (size_t)HID * DIN * 2;
    float* b1p = (float*)p; p += (size_t)HID * 4;
    float* b2p = (float*)p; p += (size_t)HID * 4;

    const int NCNT = 100000;
    const int NB = (NCNT + 2047) / 2048;  // 49

    // ---- prep (cvt + transpose + products + bias folds), independent of CSR path ----
    PrepArgs pa;
    pa.xu = x_user; pa.xbu = xb_u; pa.xi = x_item; pa.xbi = xb_i;
    TJob tj[10] = {
        {w_msg_ui0, T_msg_ui0, DIN, HID}, {w_root_ui0, T_root_ui0, DIN, HID},
        {w_msg_iu0, T_msg_iu0, DIN, HID}, {w_root_iu0, T_root_iu0, DIN, HID},
        {w_root_ui1, T_root_ui1, HID, HID}, {w_root_iu1, T_root_iu1, HID, HID},
        {w_lin_u, T_lin_u_a, HID, DOUT}, {w_lin_u + (size_t)HID * DOUT, T_lin_u_b, HID, DOUT},
        {w_lin_i, T_lin_i_a, HID, DOUT}, {w_lin_i + (size_t)HID * DOUT, T_lin_i_b, HID, DOUT},
    };
    for (int j = 0; j < 10; ++j) pa.tj[j] = tj[j];
    pa.wmui0 = w_msg_ui0; pa.wrui0 = w_root_ui0; pa.wmiu0 = w_msg_iu0; pa.wriu0 = w_root_iu0;
    pa.wmui1 = w_msg_ui1; pa.wmiu1 = w_msg_iu1;
    pa.P1 = T_P1; pa.P2 = T_P2; pa.Q1 = T_Q1; pa.Q2 = T_Q2;
    pa.bui0 = b_ui0; pa.biu0 = b_iu0; pa.bui1 = b_ui1; pa.biu1 = b_iu1;
    pa.b1p = b1p; pa.b2p = b2p;
    prep_kernel<<<CVT_B + TR_B + PROD_B + 2, 256, 0, stream>>>(pa);

    // ---- CSR build: LDS hist -> slice scan -> global scan -> LDS fill ----
    hist_lds<<<256, 256, 0, stream>>>(edge_ui + NE, edge_iu + NE, cnt_s);
    sscan<<<(NCNT + 255) / 256 + 1, 256, 0, stream>>>(cnt_s, totals);
    scan1<<<NB, 256, 0, stream>>>(totals, scan_part, NCNT);
    scan3<<<NB, 256, 0, stream>>>(totals, scan_part, NCNT, NB);
    fill_lds<<<256, 256, 0, stream>>>(edge_ui, edge_iu, cnt_s, totals, csr);
    // totals now: exclusive rowstarts; totals[100000] = 2*NE sentinel.

    // ---- level-A aggregation (DIN from raw features) ----
    {
        AggJobs2 aj = {{{totals, csr, xb_u, A_i, NI},
                        {totals + 50000, csr, xb_i, A_u, NU}}};
        agg_din<<<dim3((NI / 2 * 64) / 256, 2), 256, 0, stream>>>(aj);
    }
    // ---- level-B aggregation: B_i = mean_ui(A_u), B_u = mean_iu(A_i) ----
    {
        AggJobs2 aj = {{{totals, csr, A_u, B_i, NI},
                        {totals + 50000, csr, A_i, B_u, NU}}};
        agg_din<<<dim3((NI / 2 * 64) / 256, 2), 256, 0, stream>>>(aj);
    }

    // ---- fused GEMM stack: item0/item1 (user0/user1) live only in LDS ----
    // item: item0 = A_i@Wm0+xb_i@Wr0+b0 ; item1 = B_i@P1+A_i@P2+item0@Wr1+b1p ;
    //       z_i = item0@La + item1@Lb + b_lin
    {
        FusedJobs2 fj;
        fj.j[0] = {A_i, xb_i, B_i, T_msg_ui0, T_root_ui0, b_ui0,
                   T_P1, T_P2, T_root_ui1, b1p, T_lin_i_a, T_lin_i_b, b_lin_i, z_item};
        fj.j[1] = {A_u, xb_u, B_u, T_msg_iu0, T_root_iu0, b_iu0,
                   T_Q1, T_Q2, T_root_iu1, b2p, T_lin_u_a, T_lin_u_b, b_lin_u, z_user};
        fused_gnn<<<dim3((NU + 63) / 64, 2), 256, 0, stream>>>(fj, NU);
    }

    // ---- decode (4 edges per wave) ----
    decode_kernel<<<(((NLBL + 3) / 4) * 64 + 255) / 256, 256, 0, stream>>>(
        edge_lbl, z_user, z_item, out, NLBL);
}

// Round 2
// 398.331 us; speedup vs baseline: 1.2164x; 1.1961x over previous
//
#include <hip/hip_runtime.h>

#define NU 50000
#define NI 50000
#define NE 800000
#define NLBL 200000
#define DIN 128
#define HID 256
#define DOUT 128

#define NSLICE 64
#define SLICE_SZ 12500   // 800000 / 64
#define HALF_N 25000

typedef unsigned short ushort_t;
typedef __attribute__((ext_vector_type(8))) short bf16x8;
typedef __attribute__((ext_vector_type(4))) float f32x4;

__device__ __forceinline__ float bf2f(unsigned int u_shifted) {
    union { unsigned int i; float f; } v;
    v.i = u_shifted;
    return v.f;
}
__device__ __forceinline__ float bf_lo(unsigned int u) { return bf2f(u << 16); }
__device__ __forceinline__ float bf_hi(unsigned int u) { return bf2f(u & 0xffff0000u); }
__device__ __forceinline__ ushort_t f2bf(float f) {
    union { float f; unsigned int i; } v;
    v.f = f;
    unsigned int r = (v.i + 0x7FFFu + ((v.i >> 16) & 1u)) >> 16;
    return (ushort_t)r;
}
__device__ __forceinline__ void load_lds16(const ushort_t* g, ushort_t* s) {
    __builtin_amdgcn_global_load_lds(
        (const __attribute__((address_space(1))) void*)g,
        (__attribute__((address_space(3))) void*)s, 16, 0, 0);
}

// ================= prep1: input cvt ∥ stage-A weight products (G,S fp32) =================
// G_t = Wm_t1 @ Lb_t          [256,128]
// S_t = La_t + Wr_t1 @ Lb_t   [256,128]
#define CVT_PER 782
#define CVT_B (2 * CVT_PER)
#define SA_B 512

struct PrepArgs {
    const float* xu; ushort_t* xbu; const float* xi; ushort_t* xbi;
    const float *wm_ui1, *wr_ui1, *wm_iu1, *wr_iu1, *lin_i, *lin_u;
    float *G_i, *S_i, *G_u, *S_u;
};

__global__ __launch_bounds__(256) void prep_kernel(PrepArgs a) {
    int b = blockIdx.x;
    int t = threadIdx.x;
    if (b < CVT_B) {
        int cb = b;
        int which = (cb >= CVT_PER);
        if (which) cb -= CVT_PER;
        const float4* in = (const float4*)(which ? a.xi : a.xu);
        uint2* outp = (uint2*)(which ? a.xbi : a.xbu);
        const int n4 = NU * DIN / 4;
#pragma unroll
        for (int k = 0; k < 8; ++k) {
            int i = cb * 2048 + k * 256 + t;
            if (i < n4) {
                float4 v = in[i];
                uint2 o;
                o.x = (unsigned int)f2bf(v.x) | ((unsigned int)f2bf(v.y) << 16);
                o.y = (unsigned int)f2bf(v.z) | ((unsigned int)f2bf(v.w) << 16);
                outp[i] = o;
            }
        }
    } else {
        // stage-A products, fp32: element e of [256][128]
        int r2 = b - CVT_B;           // [0, 512)
        int which = r2 >> 7;          // 0:G_i 1:S_i 2:G_u 3:S_u
        int e = (r2 & 127) * 256 + t; // [0, 32768)
        int k = e >> 7, n = e & 127;
        const float* W = (which == 0) ? a.wm_ui1 : (which == 1) ? a.wr_ui1
                       : (which == 2) ? a.wm_iu1 : a.wr_iu1;
        const float* L = (which < 2) ? a.lin_i : a.lin_u;
        float* O = (which == 0) ? a.G_i : (which == 1) ? a.S_i
                 : (which == 2) ? a.G_u : a.S_u;
        float s = (which & 1) ? L[k * 128 + n] : 0.f;  // S adds La
#pragma unroll 4
        for (int j = 0; j < HID; ++j) s += W[k * HID + j] * L[(HID + j) * 128 + n];
        O[k * 128 + n] = s;
    }
}

// ================= prep2: V matrices (bf16, stored transposed [N=128][K=128]) + bz ====
// V1_t = Wm_own0@S_t + Wr_oth0@G_t ; V2_t = Wr_own0@S_t ; V3_t = Wm_oth0@G_t
// bz_t = b_own0@S_t + b_oth0@G_t + b_own1@Lb_t + b_lin_t
struct Prep2Args {
    const float *wm_ui0, *wr_ui0, *wm_iu0, *wr_iu0;
    const float *G_i, *S_i, *G_u, *S_u;
    const float *b_ui0, *b_iu0, *b_ui1, *b_iu1, *lin_i, *lin_u, *bl_i, *bl_u;
    ushort_t *VT1_i, *VT2_i, *VT3_i, *VT1_u, *VT2_u, *VT3_u;
    float *bz_i, *bz_u;
};

__global__ __launch_bounds__(256) void prep2_kernel(Prep2Args a) {
    int b = blockIdx.x, t = threadIdx.x;
    if (b < 384) {
        int v = b >> 6;
        int e = (b & 63) * 256 + t;   // [0, 16384)
        int k = e >> 7, n = e & 127;  // k in [0,128)
        const float *A1, *X1, *A2 = nullptr, *X2 = nullptr;
        ushort_t* O;
        switch (v) {
            case 0: A1 = a.wm_ui0; X1 = a.S_i; A2 = a.wr_iu0; X2 = a.G_i; O = a.VT1_i; break;
            case 1: A1 = a.wr_ui0; X1 = a.S_i; O = a.VT2_i; break;
            case 2: A1 = a.wm_iu0; X1 = a.G_i; O = a.VT3_i; break;
            case 3: A1 = a.wm_iu0; X1 = a.S_u; A2 = a.wr_ui0; X2 = a.G_u; O = a.VT1_u; break;
            case 4: A1 = a.wr_iu0; X1 = a.S_u; O = a.VT2_u; break;
            default: A1 = a.wm_ui0; X1 = a.G_u; O = a.VT3_u; break;
        }
        float s = 0.f;
#pragma unroll 4
        for (int j = 0; j < HID; ++j) s += A1[k * HID + j] * X1[j * 128 + n];
        if (A2) {
#pragma unroll 4
            for (int j = 0; j < HID; ++j) s += A2[k * HID + j] * X2[j * 128 + n];
        }
        O[n * 128 + k] = f2bf(s);
    } else {
        if (t >= 128) return;
        int user = b - 384;  // 0: item, 1: user
        int n = t;
        const float* S = user ? a.S_u : a.S_i;
        const float* G = user ? a.G_u : a.G_i;
        const float* b_own0 = user ? a.b_iu0 : a.b_ui0;
        const float* b_oth0 = user ? a.b_ui0 : a.b_iu0;
        const float* b_own1 = user ? a.b_iu1 : a.b_ui1;
        const float* lin = user ? a.lin_u : a.lin_i;
        const float* bl = user ? a.bl_u : a.bl_i;
        float* o = user ? a.bz_u : a.bz_i;
        float s = bl[n];
        for (int j = 0; j < HID; ++j)
            s += b_own0[j] * S[j * 128 + n] + b_oth0[j] * G[j * 128 + n] +
                 b_own1[j] * lin[(HID + j) * 128 + n];
        o[n] = s;
    }
}

// ================= LDS counting-sort CSR build (ZERO global atomics) =================
__global__ __launch_bounds__(256) void hist_lds(const int* __restrict__ dui,
                                                const int* __restrict__ diu,
                                                ushort_t* __restrict__ cnt_s) {
    __shared__ unsigned int cnt[HALF_N / 2];
    int b = blockIdx.x, t = threadIdx.x;
    int g = b >> 7, s = (b >> 1) & 63, half = b & 1;
    for (int i = t; i < HALF_N / 2; i += 256) cnt[i] = 0;
    __syncthreads();
    const int* dst = g ? diu : dui;
    int hbase = half * HALF_N;
    int e0 = s * SLICE_SZ;
    for (int i = e0 + t; i < e0 + SLICE_SZ; i += 256) {
        int d = dst[i] - hbase;
        if ((unsigned)d < (unsigned)HALF_N)
            atomicAdd(&cnt[d >> 1], 1u << ((d & 1) * 16));
    }
    __syncthreads();
    unsigned int* outp = (unsigned int*)(cnt_s + ((size_t)(g * NSLICE + s)) * 50000 + hbase);
    for (int i = t; i < HALF_N / 2; i += 256) outp[i] = cnt[i];
}

__global__ __launch_bounds__(256) void sscan(ushort_t* __restrict__ cnt_s, int* __restrict__ totals) {
    int idx = blockIdx.x * 256 + threadIdx.x;
    if (idx == 0) totals[100000] = 2 * NE;  // sentinel: end of user-graph csr
    if (idx >= 100000) return;
    int g = idx / 50000, node = idx - g * 50000;
    size_t base = (size_t)g * NSLICE * 50000 + node;
    int run = 0;
#pragma unroll 4
    for (int s = 0; s < NSLICE; ++s) {
        size_t o = base + (size_t)s * 50000;
        int c = cnt_s[o];
        cnt_s[o] = (ushort_t)run;
        run += c;
    }
    totals[idx] = run;
}

__global__ __launch_bounds__(256) void scan1(const int* __restrict__ d, int* __restrict__ part, int n) {
    __shared__ int wsum[4];
    int b = blockIdx.x, t = threadIdx.x;
    int i0 = b * 2048 + t * 8;
    int s = 0;
#pragma unroll
    for (int k = 0; k < 8; ++k) s += (i0 + k < n) ? d[i0 + k] : 0;
#pragma unroll
    for (int off = 32; off > 0; off >>= 1) s += __shfl_down(s, off, 64);
    if ((t & 63) == 0) wsum[t >> 6] = s;
    __syncthreads();
    if (t == 0) part[b] = wsum[0] + wsum[1] + wsum[2] + wsum[3];
}

__global__ __launch_bounds__(256) void scan3(int* __restrict__ d, const int* __restrict__ part,
                                             int n, int nb) {
    __shared__ int wsum[4];
    __shared__ int blockoff_sh;
    int b = blockIdx.x, t = threadIdx.x;
    int lane = t & 63, wv = t >> 6;
    if (t < 64) {
        int v = (t < nb) ? part[t] : 0;
        int incl = v;
#pragma unroll
        for (int off = 1; off < 64; off <<= 1) {
            int tv = __shfl_up(incl, off, 64);
            if (t >= off) incl += tv;
        }
        if (t == b) blockoff_sh = incl - v;
    }
    int i0 = b * 2048 + t * 8;
    int v[8];
    int tsum = 0;
#pragma unroll
    for (int k = 0; k < 8; ++k) {
        v[k] = (i0 + k < n) ? d[i0 + k] : 0;
        tsum += v[k];
    }
    int incl = tsum;
#pragma unroll
    for (int off = 1; off < 64; off <<= 1) {
        int tv = __shfl_up(incl, off, 64);
        if (lane >= off) incl += tv;
    }
    if (lane == 63) wsum[wv] = incl;
    __syncthreads();
    int woff = 0;
    for (int w = 0; w < wv; ++w) woff += wsum[w];
    int run = blockoff_sh + woff + (incl - tsum);
#pragma unroll
    for (int k = 0; k < 8; ++k) {
        if (i0 + k < n) d[i0 + k] = run;
        run += v[k];
    }
}

__global__ __launch_bounds__(256) void fill_lds(const int* __restrict__ eui,
                                                const int* __restrict__ eiu,
                                                const ushort_t* __restrict__ cnt_s,
                                                const int* __restrict__ rowstart,
                                                ushort_t* __restrict__ csr) {
    __shared__ unsigned int off[HALF_N / 2];
    int b = blockIdx.x, t = threadIdx.x;
    int g = b >> 7, s = (b >> 1) & 63, half = b & 1;
    const unsigned int* st =
        (const unsigned int*)(cnt_s + ((size_t)(g * NSLICE + s)) * 50000 + half * HALF_N);
    for (int i = t; i < HALF_N / 2; i += 256) off[i] = st[i];
    __syncthreads();
    const int* src = g ? eiu : eui;
    const int* dst = src + NE;
    const int* rs = rowstart + g * 50000;
    int hbase = half * HALF_N;
    int e0 = s * SLICE_SZ;
    for (int i = e0 + t; i < e0 + SLICE_SZ; i += 256) {
        int dd = dst[i];
        int d = dd - hbase;
        if ((unsigned)d < (unsigned)HALF_N) {
            unsigned old = atomicAdd(&off[d >> 1], 1u << ((d & 1) * 16));
            int rel = (int)((old >> ((d & 1) * 16)) & 0xffffu);
            csr[(size_t)rs[dd] + rel] = (ushort_t)src[i];
        }
    }
}

// ================= DIN=128 gather mean aggregation (bf16, fp32 accum), 2 jobs =================
struct AggJob { const int* sp; const ushort_t* csr; const ushort_t* x; ushort_t* out; int n; };
struct AggJobs2 { AggJob j[2]; };

__global__ __launch_bounds__(256) void agg_din(AggJobs2 js) {
    AggJob jb = js.j[blockIdx.y];
    int wave = (int)((blockIdx.x * 256u + threadIdx.x) >> 6);
    int lane = threadIdx.x & 63;
    const int l = lane & 31;
    const int h = lane >> 5;
    int w2 = wave * 2;
    if (w2 >= jb.n) return;
    int w = w2 + h;
    int s0 = jb.sp[w];
    int s1 = jb.sp[w + 1];
    int cnt = s1 - s0;
    float sc = (cnt > 0) ? 1.0f / (float)cnt : 0.0f;
    int cother = __shfl_xor(cnt, 32, 64);
    int cmax = (cnt > cother) ? cnt : cother;
    const uint2* xp = (const uint2*)jb.x;  // row = 32 uint2
    float f0 = 0.f, f1 = 0.f, f2 = 0.f, f3 = 0.f;
    float g0 = 0.f, g1 = 0.f, g2 = 0.f, g3 = 0.f;
    for (int chunk = 0; chunk < cmax; chunk += 32) {
        int mh = cnt - chunk;
        int safe = (mh > 0) ? ((l < mh) ? l : mh - 1) : 0;
        int vidx = (int)jb.csr[s0 + chunk + safe];
        int mm = cmax - chunk;
        if (mm > 32) mm = 32;
        int j = 0;
        for (; j + 3 < mm; j += 4) {
            int i0 = __shfl(vidx, j, 32);
            int i1 = __shfl(vidx, j + 1, 32);
            int i2 = __shfl(vidx, j + 2, 32);
            int i3 = __shfl(vidx, j + 3, 32);
            float m0 = (j < mh) ? 1.f : 0.f;
            float m1 = (j + 1 < mh) ? 1.f : 0.f;
            float m2 = (j + 2 < mh) ? 1.f : 0.f;
            float m3 = (j + 3 < mh) ? 1.f : 0.f;
            uint2 u0 = xp[(size_t)((j < mh) ? i0 : 0) * 32 + l];
            uint2 u1 = xp[(size_t)((j + 1 < mh) ? i1 : 0) * 32 + l];
            uint2 u2 = xp[(size_t)((j + 2 < mh) ? i2 : 0) * 32 + l];
            uint2 u3 = xp[(size_t)((j + 3 < mh) ? i3 : 0) * 32 + l];
            f0 = fmaf(m0, bf_lo(u0.x), f0); f1 = fmaf(m0, bf_hi(u0.x), f1);
            f2 = fmaf(m0, bf_lo(u0.y), f2); f3 = fmaf(m0, bf_hi(u0.y), f3);
            g0 = fmaf(m1, bf_lo(u1.x), g0); g1 = fmaf(m1, bf_hi(u1.x), g1);
            g2 = fmaf(m1, bf_lo(u1.y), g2); g3 = fmaf(m1, bf_hi(u1.y), g3);
            f0 = fmaf(m2, bf_lo(u2.x), f0); f1 = fmaf(m2, bf_hi(u2.x), f1);
            f2 = fmaf(m2, bf_lo(u2.y), f2); f3 = fmaf(m2, bf_hi(u2.y), f3);
            g0 = fmaf(m3, bf_lo(u3.x), g0); g1 = fmaf(m3, bf_hi(u3.x), g1);
            g2 = fmaf(m3, bf_lo(u3.y), g2); g3 = fmaf(m3, bf_hi(u3.y), g3);
        }
        for (; j < mm; ++j) {
            int i0 = __shfl(vidx, j, 32);
            float m0 = (j < mh) ? 1.f : 0.f;
            uint2 u0 = xp[(size_t)((j < mh) ? i0 : 0) * 32 + l];
            f0 = fmaf(m0, bf_lo(u0.x), f0); f1 = fmaf(m0, bf_hi(u0.x), f1);
            f2 = fmaf(m0, bf_lo(u0.y), f2); f3 = fmaf(m0, bf_hi(u0.y), f3);
        }
    }
    uint2 o;
    o.x = (unsigned int)f2bf((f0 + g0) * sc) | ((unsigned int)f2bf((f1 + g1) * sc) << 16);
    o.y = (unsigned int)f2bf((f2 + g2) * sc) | ((unsigned int)f2bf((f3 + g3) * sc) << 16);
    ((uint2*)jb.out)[(size_t)w * 32 + l] = o;
}

// ================= MFMA GEMM: C = sum_p A[p]@W[p] + bias, NP parts, 2 jobs =================
// Tile 128x128, BK=32, 4 waves (2x2), each 4x4 frags of 16x16x32 (round-7 proven config).
struct GemmJob {
    const ushort_t* A[3];
    const ushort_t* WT[3];
    int K[3];
    const float* bias;
    void* C;
};
struct GemmJobs2 { GemmJob j[2]; };

template <int NP, typename OutT>
__global__ __launch_bounds__(256) void gemmN(GemmJobs2 js, int M, int N) {
    GemmJob jb = js.j[blockIdx.z];
    __shared__ ushort_t sA[128 * 32];
    __shared__ ushort_t sB[128 * 32];
    const int tid = threadIdx.x;
    const int lane = tid & 63;
    const int wv = tid >> 6;
    const int wm = wv & 1, wn = wv >> 1;
    const int bm = blockIdx.y * 128, bn = blockIdx.x * 128;

    f32x4 acc[4][4] = {};

    const int srow = tid >> 2;
    const int scol = (tid & 3) * 8;

#pragma unroll
    for (int part = 0; part < NP; ++part) {
        const ushort_t* A = jb.A[part];
        const ushort_t* WT = jb.WT[part];
        const int K = jb.K[part];
        int ar0 = bm + srow;       if (ar0 > M - 1) ar0 = M - 1;
        int ar1 = bm + 64 + srow;  if (ar1 > M - 1) ar1 = M - 1;
        const size_t aoff0 = (size_t)ar0 * K + scol;
        const size_t aoff1 = (size_t)ar1 * K + scol;
        const size_t boff0 = (size_t)(bn + srow) * K + scol;
        const size_t boff1 = (size_t)(bn + 64 + srow) * K + scol;
        for (int k0 = 0; k0 < K; k0 += 32) {
            __syncthreads();
            load_lds16(A + aoff0 + k0, sA + tid * 8);
            load_lds16(A + aoff1 + k0, sA + 2048 + tid * 8);
            load_lds16(WT + boff0 + k0, sB + tid * 8);
            load_lds16(WT + boff1 + k0, sB + 2048 + tid * 8);
            __syncthreads();
            const ushort_t* pA = sA + ((wm * 64 + (lane & 15)) * 32 + (lane >> 4) * 8);
            const ushort_t* pB = sB + ((wn * 64 + (lane & 15)) * 32 + (lane >> 4) * 8);
            bf16x8 af[4], bfr[4];
#pragma unroll
            for (int mt = 0; mt < 4; ++mt) af[mt] = *(const bf16x8*)(pA + mt * 512);
#pragma unroll
            for (int nt = 0; nt < 4; ++nt) bfr[nt] = *(const bf16x8*)(pB + nt * 512);
#pragma unroll
            for (int mt = 0; mt < 4; ++mt)
#pragma unroll
                for (int nt = 0; nt < 4; ++nt)
                    acc[mt][nt] = __builtin_amdgcn_mfma_f32_16x16x32_bf16(
                        af[mt], bfr[nt], acc[mt][nt], 0, 0, 0);
        }
    }

#pragma unroll
    for (int mt = 0; mt < 4; ++mt) {
#pragma unroll
        for (int r = 0; r < 4; ++r) {
            int row = bm + wm * 64 + mt * 16 + (lane >> 4) * 4 + r;
            if (row >= M) continue;
#pragma unroll
            for (int nt = 0; nt < 4; ++nt) {
                int col = bn + wn * 64 + nt * 16 + (lane & 15);
                float v = acc[mt][nt][r] + jb.bias[col];
                if constexpr (sizeof(OutT) == 2)
                    ((ushort_t*)jb.C)[(size_t)row * N + col] = f2bf(v);
                else
                    ((float*)jb.C)[(size_t)row * N + col] = v;
            }
        }
    }
}

// ================= decode: bf16 z, 4 edges per wave (16-lane quarters, uint4) =================
__global__ void decode_kernel(const int* __restrict__ lbl, const ushort_t* __restrict__ zu,
                              const ushort_t* __restrict__ zi, float* __restrict__ out, int n) {
    int gid = blockIdx.x * blockDim.x + threadIdx.x;
    int wave = gid >> 6;
    int lane = threadIdx.x & 63;
    int q = lane >> 4;
    int l = lane & 15;
    int e = wave * 4 + q;
    if (e >= n) return;
    int u = lbl[e];
    int it = lbl[n + e];
    uint4 a = ((const uint4*)zu)[(size_t)u * 16 + l];
    uint4 b = ((const uint4*)zi)[(size_t)it * 16 + l];
    float s = bf_lo(a.x) * bf_lo(b.x) + bf_hi(a.x) * bf_hi(b.x) +
              bf_lo(a.y) * bf_lo(b.y) + bf_hi(a.y) * bf_hi(b.y) +
              bf_lo(a.z) * bf_lo(b.z) + bf_hi(a.z) * bf_hi(b.z) +
              bf_lo(a.w) * bf_lo(b.w) + bf_hi(a.w) * bf_hi(b.w);
#pragma unroll
    for (int off = 8; off > 0; off >>= 1) s += __shfl_down(s, off, 16);
    if (l == 0) out[e] = s;
}

extern "C" void kernel_launch(void* const* d_in, const int* in_sizes, int n_in,
                              void* d_out, int out_size, void* d_ws, size_t ws_size,
                              hipStream_t stream) {
    const float* x_user = (const float*)d_in[0];
    const float* x_item = (const float*)d_in[1];
    const int* edge_ui = (const int*)d_in[2];   // row0=src(user), row1=dst(item)
    const int* edge_iu = (const int*)d_in[3];   // row0=src(item), row1=dst(user)
    const int* edge_lbl = (const int*)d_in[4];
    const float* w_msg_ui0 = (const float*)d_in[5];
    const float* b_ui0 = (const float*)d_in[6];
    const float* w_root_ui0 = (const float*)d_in[7];
    const float* w_msg_iu0 = (const float*)d_in[8];
    const float* b_iu0 = (const float*)d_in[9];
    const float* w_root_iu0 = (const float*)d_in[10];
    const float* w_msg_ui1 = (const float*)d_in[11];
    const float* b_ui1 = (const float*)d_in[12];
    const float* w_root_ui1 = (const float*)d_in[13];
    const float* w_msg_iu1 = (const float*)d_in[14];
    const float* b_iu1 = (const float*)d_in[15];
    const float* w_root_iu1 = (const float*)d_in[16];
    const float* w_lin_u = (const float*)d_in[17];  // [512,128]
    const float* b_lin_u = (const float*)d_in[18];
    const float* w_lin_i = (const float*)d_in[19];
    const float* b_lin_i = (const float*)d_in[20];
    float* out = (float*)d_out;

    // ---- workspace layout (head kept identical to prior rounds) ----
    char* p = (char*)d_ws;
    ushort_t* user0 = (ushort_t*)p;  p += (size_t)NU * HID * 2;
    ushort_t* item0 = (ushort_t*)p;  p += (size_t)NI * HID * 2;
    ushort_t* user1 = (ushort_t*)p;  p += (size_t)NU * HID * 2;
    ushort_t* item1 = (ushort_t*)p;  p += (size_t)NI * HID * 2;
    (void)user0; (void)item0; (void)user1; (void)item1;
    ushort_t* A_i  = (ushort_t*)p;   p += (size_t)NI * DIN * 2;  // mean_ui(x_user)
    ushort_t* A_u  = (ushort_t*)p;   p += (size_t)NU * DIN * 2;  // mean_iu(x_item)
    ushort_t* B_i  = (ushort_t*)p;   p += (size_t)NI * DIN * 2;  // mean_ui(A_u)
    ushort_t* B_u  = (ushort_t*)p;   p += (size_t)NU * DIN * 2;  // mean_iu(A_i)
    ushort_t* xb_u  = (ushort_t*)p;  p += (size_t)NU * DIN * 2;
    ushort_t* xb_i  = (ushort_t*)p;  p += (size_t)NI * DIN * 2;
    ushort_t* z_user = (ushort_t*)p; p += (size_t)NU * DOUT * 2;
    ushort_t* z_item = (ushort_t*)p; p += (size_t)NI * DOUT * 2;
    int* totals     = (int*)p;       p += (size_t)(100000 + 64) * 4;  // rowstarts + sentinel
    ushort_t* csr   = (ushort_t*)p;  p += (size_t)2 * NE * 2;  // [0,NE): ui; [NE,2NE): iu
    ushort_t* cnt_s = (ushort_t*)p;  p += (size_t)2 * NSLICE * 50000 * 2;  // per-slice counts
    int* scan_part  = (int*)p;       p += 64 * 4;
    // ---- folded-weight buffers (replaces old T_* region; smaller) ----
    float* G_i = (float*)p; p += (size_t)HID * 128 * 4;
    float* S_i = (float*)p; p += (size_t)HID * 128 * 4;
    float* G_u = (float*)p; p += (size_t)HID * 128 * 4;
    float* S_u = (float*)p; p += (size_t)HID * 128 * 4;
    ushort_t* VT1_i = (ushort_t*)p; p += (size_t)128 * 128 * 2;
    ushort_t* VT2_i = (ushort_t*)p; p += (size_t)128 * 128 * 2;
    ushort_t* VT3_i = (ushort_t*)p; p += (size_t)128 * 128 * 2;
    ushort_t* VT1_u = (ushort_t*)p; p += (size_t)128 * 128 * 2;
    ushort_t* VT2_u = (ushort_t*)p; p += (size_t)128 * 128 * 2;
    ushort_t* VT3_u = (ushort_t*)p; p += (size_t)128 * 128 * 2;
    float* bz_i = (float*)p; p += 128 * 4;
    float* bz_u = (float*)p; p += 128 * 4;

    const int NCNT = 100000;
    const int NB = (NCNT + 2047) / 2048;  // 49

    // ---- prep1: cvt + stage-A weight products ----
    PrepArgs pa;
    pa.xu = x_user; pa.xbu = xb_u; pa.xi = x_item; pa.xbi = xb_i;
    pa.wm_ui1 = w_msg_ui1; pa.wr_ui1 = w_root_ui1;
    pa.wm_iu1 = w_msg_iu1; pa.wr_iu1 = w_root_iu1;
    pa.lin_i = w_lin_i; pa.lin_u = w_lin_u;
    pa.G_i = G_i; pa.S_i = S_i; pa.G_u = G_u; pa.S_u = S_u;
    prep_kernel<<<CVT_B + SA_B, 256, 0, stream>>>(pa);

    // ---- prep2: V matrices + folded bias ----
    Prep2Args p2;
    p2.wm_ui0 = w_msg_ui0; p2.wr_ui0 = w_root_ui0;
    p2.wm_iu0 = w_msg_iu0; p2.wr_iu0 = w_root_iu0;
    p2.G_i = G_i; p2.S_i = S_i; p2.G_u = G_u; p2.S_u = S_u;
    p2.b_ui0 = b_ui0; p2.b_iu0 = b_iu0; p2.b_ui1 = b_ui1; p2.b_iu1 = b_iu1;
    p2.lin_i = w_lin_i; p2.lin_u = w_lin_u; p2.bl_i = b_lin_i; p2.bl_u = b_lin_u;
    p2.VT1_i = VT1_i; p2.VT2_i = VT2_i; p2.VT3_i = VT3_i;
    p2.VT1_u = VT1_u; p2.VT2_u = VT2_u; p2.VT3_u = VT3_u;
    p2.bz_i = bz_i; p2.bz_u = bz_u;
    prep2_kernel<<<386, 256, 0, stream>>>(p2);

    // ---- CSR build: LDS hist -> slice scan -> global scan -> LDS fill ----
    hist_lds<<<256, 256, 0, stream>>>(edge_ui + NE, edge_iu + NE, cnt_s);
    sscan<<<(NCNT + 255) / 256 + 1, 256, 0, stream>>>(cnt_s, totals);
    scan1<<<NB, 256, 0, stream>>>(totals, scan_part, NCNT);
    scan3<<<NB, 256, 0, stream>>>(totals, scan_part, NCNT, NB);
    fill_lds<<<256, 256, 0, stream>>>(edge_ui, edge_iu, cnt_s, totals, csr);
    // totals now: exclusive rowstarts; totals[100000] = 2*NE sentinel.

    // ---- level-A aggregation (DIN from raw features) ----
    {
        AggJobs2 aj = {{{totals, csr, xb_u, A_i, NI},
                        {totals + 50000, csr, xb_i, A_u, NU}}};
        agg_din<<<dim3((NI / 2 * 64) / 256, 2), 256, 0, stream>>>(aj);
    }
    // ---- level-B aggregation: B_i = mean_ui(A_u), B_u = mean_iu(A_i) ----
    {
        AggJobs2 aj = {{{totals, csr, A_u, B_i, NI},
                        {totals + 50000, csr, A_i, B_u, NU}}};
        agg_din<<<dim3((NI / 2 * 64) / 256, 2), 256, 0, stream>>>(aj);
    }

    // ---- single fused-weight GEMM: z = A@V1 + xb@V2 + B@V3 + bz ----
    {
        GemmJobs2 gj = {{{{A_i, xb_i, B_i}, {VT1_i, VT2_i, VT3_i}, {DIN, DIN, DIN}, bz_i, z_item},
                         {{A_u, xb_u, B_u}, {VT1_u, VT2_u, VT3_u}, {DIN, DIN, DIN}, bz_u, z_user}}};
        gemmN<3, ushort_t><<<dim3(DOUT / 128, (NU + 127) / 128, 2), 256, 0, stream>>>(gj, NU, DOUT);
    }

    // ---- decode (4 edges per wave) ----
    decode_kernel<<<(((NLBL + 3) / 4) * 64 + 255) / 256, 256, 0, stream>>>(
        edge_lbl, z_user, z_item, out, NLBL);
}